// Round 8
// baseline (383.856 us; speedup 1.0000x reference)
//
#include <hip/hip_runtime.h>
#include <stdint.h>

typedef __attribute__((ext_vector_type(8))) short short8;
typedef __attribute__((ext_vector_type(16))) float f32x16;

#define HP 130
#define WPAD 258
#define CIN 256

#define AS1 __attribute__((address_space(1)))
#define AS3 __attribute__((address_space(3)))

__device__ __forceinline__ unsigned short f2bf(float f) {
  unsigned int x = __float_as_uint(f);
  x = x + 0x7fffu + ((x >> 16) & 1u);
  return (unsigned short)(x >> 16);
}

// ---------------- mu[b,j,o] = relu(fc_w[j] @ style[b,j] + fc_b[j]) ----------------
__global__ __launch_bounds__(128) void k_mu(const float* __restrict__ sty,
    const float* __restrict__ fcw, const float* __restrict__ fcb,
    float* __restrict__ mu)
{
  int bj = blockIdx.x;            // 140 = 4*35
  int b = bj / 35, j = bj - 35 * b;
  int o = threadIdx.x;            // 128
  __shared__ float ss[128];
  ss[o] = sty[((size_t)b * 35 + j) * 128 + o];
  __syncthreads();
  const float4* wr = (const float4*)(fcw + ((size_t)j * 128 + o) * 128);
  const float4* sv = (const float4*)ss;
  float acc = fcb[j * 128 + o];
  #pragma unroll 8
  for (int d = 0; d < 32; ++d) {
    float4 wv = wr[d], s4 = sv[d];
    acc += wv.x * s4.x + wv.y * s4.y + wv.z * s4.z + wv.w * s4.w;
  }
  mu[((size_t)b * 35 + j) * 128 + o] = fmaxf(acc, 0.f);
}

// ---------------- mlpT[j][tap][o] transpose + blended biases ----------------
__global__ __launch_bounds__(256) void k_prep(const float* __restrict__ mlpw,
    float* __restrict__ mlpT,
    const float* __restrict__ cgb, const float* __restrict__ cbb,
    const float* __restrict__ sgb, const float* __restrict__ sbb,
    const float* __restrict__ blg, const float* __restrict__ blb,
    float* __restrict__ bias)
{
  int t = blockIdx.x * 256 + threadIdx.x;
  if (t < 40320) {
    int o = t & 127;
    int jt = t >> 7;                 // j*9 + tap, 0..314
    mlpT[(size_t)jt * 128 + o] = mlpw[((size_t)o * 35 + (jt / 9)) * 9 + (jt % 9)];
  }
  if (t < 256) {
    float ga = 1.f / (1.f + expf(-blg[0]));
    float ba = 1.f / (1.f + expf(-blb[0]));
    bias[t]       = ga * cgb[t] + (1.f - ga) * sgb[t];
    bias[256 + t] = ba * cbb[t] + (1.f - ba) * sbb[t];
  }
}

// ---------------- packed, blended bf16 weights for 32x32x16 MFMA -------------------
// uint4 pos = ((((vfgrp*8 + cc)*9 + tap)*2 + mf)*2 + ks)*64 + lane
// lane provides: v = vfgrp*64 + mf*32 + (lane&31);  ci = cc*32 + ks*16 + (lane>>5)*8 + j
// (A and B use the SAME (lane-half, j)->ci permutation -> correct sum regardless of hw k map)
__global__ __launch_bounds__(256) void k_pack(
    const float* __restrict__ cgw, const float* __restrict__ cbw,
    const float* __restrict__ sgw, const float* __restrict__ sbw,
    const float* __restrict__ blg, const float* __restrict__ blb,
    unsigned short* __restrict__ Wp)
{
  int gid = blockIdx.x * 256 + threadIdx.x;   // 147456 exactly
  int lane = gid & 63;
  int sub = (gid >> 6) & 3;
  int mf = sub >> 1, ks = sub & 1;
  int u2 = gid >> 8;
  int tap = u2 % 9;
  int u3 = u2 / 9;
  int cc = u3 & 7;
  int vfgrp = u3 >> 3;
  int v = vfgrp * 64 + mf * 32 + (lane & 31);
  int c = v >> 1, g = v & 1;
  int ci0 = cc * 32 + ks * 16 + (lane >> 5) * 8;
  float ga = 1.f / (1.f + expf(-blg[0]));
  float ba = 1.f / (1.f + expf(-blb[0]));
  float sc = g ? ba : ga;
  const float* wavg = g ? cbw : cgw;
  const float* wsp  = g ? sbw : sgw;
  union { uint4 v4; unsigned short s[8]; } u;
  #pragma unroll
  for (int jj = 0; jj < 8; ++jj) {
    int ci = ci0 + jj;
    float val;
    if (ci < 128) val = sc * wavg[((size_t)c * 128 + ci) * 9 + tap];
    else          val = (1.f - sc) * wsp[((size_t)c * 128 + (ci - 128)) * 9 + tap];
    u.s[jj] = f2bf(val);
  }
  ((uint4*)Wp)[gid] = u.v4;
}

// ---------------- instance-norm stats: mean + rstd per (b,c) ----------------
__global__ __launch_bounds__(256) void k_stats(const float* __restrict__ x,
                                               float* __restrict__ stats)
{
  int bc = blockIdx.x;                      // 1024
  const float* p = x + (size_t)bc * 32768;
  int t = threadIdx.x;
  float s = 0.f, s2 = 0.f;
  #pragma unroll 4
  for (int i = 0; i < 32; ++i) {
    float4 v = *(const float4*)(p + (size_t)i * 1024 + t * 4);
    s  += v.x + v.y + v.z + v.w;
    s2 += v.x * v.x + v.y * v.y + v.z * v.z + v.w * v.w;
  }
  #pragma unroll
  for (int off2 = 32; off2 > 0; off2 >>= 1) {
    s  += __shfl_down(s, off2);
    s2 += __shfl_down(s2, off2);
  }
  __shared__ float red[8];
  int lane = t & 63, wv = t >> 6;
  if (lane == 0) { red[wv] = s; red[4 + wv] = s2; }
  __syncthreads();
  if (t == 0) {
    float S  = red[0] + red[1] + red[2] + red[3];
    float S2 = red[4] + red[5] + red[6] + red[7];
    float mean = S * (1.f / 32768.f);
    float var  = S2 * (1.f / 32768.f) - mean * mean;
    stats[bc] = mean;
    stats[1024 + bc] = rsqrtf(var + 1e-5f);
  }
}

// ---------------- zero only the halo ring of U (interior fully rewritten by k_build) ----
__global__ __launch_bounds__(256) void k_halo(uint4* __restrict__ U4)
{
  int t = blockIdx.x * 256 + threadIdx.x;
  if (t >= 98816) return;               // 3088 halo pixels * 32 uint4
  int sub = t & 31, pi = t >> 5;
  int b = pi / 772, r = pi - b * 772;
  int h, w;
  if (r < 258)      { h = 0;   w = r; }
  else if (r < 516) { h = 129; w = r - 258; }
  else if (r < 644) { h = r - 516 + 1; w = 0; }
  else              { h = r - 644 + 1; w = 257; }
  U4[((size_t)(b * HP + h) * WPAD + w) * 32 + sub] = (uint4){0, 0, 0, 0};
}

// ---------------- build padded channel-last bf16 input U[b][h+1][w+1][256] ----------------
__global__ __launch_bounds__(256) void k_build(const int* __restrict__ seg,
    const float* __restrict__ mu, const float* __restrict__ mlpT,
    const float* __restrict__ mlpb, unsigned short* __restrict__ U)
{
  int blk = blockIdx.x;             // 16384
  int b = blk >> 12, rem = blk & 4095;
  int h = rem >> 5, w0 = (rem & 31) << 3;
  int t = threadIdx.x;
  int p = t >> 5, q = t & 31;
  int w = w0 + p;
  unsigned short* up = U + (((size_t)(b * HP + h + 1)) * WPAD + (w + 1)) * CIN;
  union { uint4 v4; unsigned short s[8]; } u;
  if (q < 16) {
    int lab = seg[((size_t)b * 128 + h) * 256 + w];
    const float4* mrow = (const float4*)(mu + ((size_t)(b * 35 + lab)) * 128 + q * 8);
    float4 v0 = mrow[0], v1 = mrow[1];
    u.s[0] = f2bf(v0.x); u.s[1] = f2bf(v0.y); u.s[2] = f2bf(v0.z); u.s[3] = f2bf(v0.w);
    u.s[4] = f2bf(v1.x); u.s[5] = f2bf(v1.y); u.s[6] = f2bf(v1.z); u.s[7] = f2bf(v1.w);
    *(uint4*)(up + q * 8) = u.v4;
  } else {
    int o0 = (q - 16) * 8;
    float a[8];
    #pragma unroll
    for (int j = 0; j < 8; ++j) a[j] = mlpb[o0 + j];
    #pragma unroll
    for (int kh = 0; kh < 3; ++kh) {
      int hh = h + kh - 1;
      if ((unsigned)hh < 128u) {
        #pragma unroll
        for (int kw = 0; kw < 3; ++kw) {
          int ww = w + kw - 1;
          if ((unsigned)ww < 256u) {
            int lab2 = seg[((size_t)b * 128 + hh) * 256 + ww];
            const float4* wr = (const float4*)(mlpT + ((size_t)lab2 * 9 + kh * 3 + kw) * 128 + o0);
            float4 v0 = wr[0], v1 = wr[1];
            a[0] += v0.x; a[1] += v0.y; a[2] += v0.z; a[3] += v0.w;
            a[4] += v1.x; a[5] += v1.y; a[6] += v1.z; a[7] += v1.w;
          }
        }
      }
    }
    #pragma unroll
    for (int j = 0; j < 8; ++j) u.s[j] = f2bf(fmaxf(a[j], 0.f));
    *(uint4*)(up + 128 + o0) = u.v4;
  }
}

// ---------------- main fused conv, 32x32x16 MFMA version ----------------
// 4 waves x (64v x 128px); wave = 2 m-frags(32v) x 4 n-frags(32px); K-chunk 32 = 2 ksteps.
// LDS layout: uint4 slot L = (r*4 + sl)*130 + px holds U[h0+r][w0+px][cc*32+sl*8 ..+8].
// B-frag read: lane l -> byte (kh*4 + ks*2 + (l>>5))*2080 + (kw + nf*32 + (l&31))*16
//   = pbase + compile-time-imm  -> lane-contiguous ds_read_b128, conflict-free, no swizzle.
// Wait skeleton identical to R7 (counted vmcnt, STG 2-tap windows).
// __launch_bounds__(256,2): acc(128) + arch(~128) = full 256/wave; (256,3) spills (R6).

#define WAITV_(vm, lg) asm volatile("s_waitcnt vmcnt(" #vm ") lgkmcnt(" #lg ")" ::: "memory")
#define WAITV(vm, lg) do { WAITV_(vm, lg); __builtin_amdgcn_sched_barrier(0); } while (0)
#define WAITL(lg) do { asm volatile("s_waitcnt lgkmcnt(" #lg ")" ::: "memory"); __builtin_amdgcn_sched_barrier(0); } while (0)

#define MM(AS, BS, KS) do {                                                    \
    __builtin_amdgcn_s_setprio(1);                                             \
    _Pragma("unroll")                                                          \
    for (int mf_ = 0; mf_ < 2; ++mf_)                                          \
      _Pragma("unroll")                                                        \
      for (int nf_ = 0; nf_ < 4; ++nf_)                                        \
        acc[mf_][nf_] = __builtin_amdgcn_mfma_f32_32x32x16_bf16(               \
            afr##AS[mf_ * 2 + (KS)], bfr##BS[nf_], acc[mf_][nf_], 0, 0, 0);    \
    __builtin_amdgcn_s_setprio(0);                                             \
  } while (0)

#define LOADA(NS) do {                                                         \
    aptr += 4096;                                                              \
    afr##NS[0] = *(const short8*)(aptr);                                       \
    afr##NS[1] = *(const short8*)(aptr + 1024);                                \
    afr##NS[2] = *(const short8*)(aptr + 2048);                                \
    afr##NS[3] = *(const short8*)(aptr + 3072);                                \
  } while (0)

#define BOFF(T, KS) (((T) / 3) * 8320 + ((T) % 3) * 16 + (KS) * 4160)
#define LOADB(NS, T, KS) do {                                                  \
    bfr##NS[0] = *(const short8*)(lbuf + pbase + BOFF(T, KS));                 \
    bfr##NS[1] = *(const short8*)(lbuf + pbase + BOFF(T, KS) + 512);           \
    bfr##NS[2] = *(const short8*)(lbuf + pbase + BOFF(T, KS) + 1024);          \
    bfr##NS[3] = *(const short8*)(lbuf + pbase + BOFF(T, KS) + 1536);          \
  } while (0)

#define STG(SI) do {                                                           \
    __builtin_amdgcn_global_load_lds((const AS1 unsigned int*)gsrc[SI],        \
        (AS3 unsigned int*)((SI) < 6 ? (stbw + (SI) * 4096) : (stb + 24576)),  \
        16, 0, 0);                                                             \
    gsrc[SI] += 64;                                                            \
  } while (0)

__global__ __launch_bounds__(256, 2) void k_conv(
    const float* __restrict__ x, const uint4* __restrict__ U,
    const char* __restrict__ Wp, const float* __restrict__ bias,
    const float* __restrict__ stats, float* __restrict__ out)
{
  int bid = blockIdx.x;                // 2048
  int xcd = bid & 7, i0 = bid >> 3;    // i0: 0..255
  int pt = xcd * 128 + (i0 >> 1);      // mt fastest within an XCD
  int mt = i0 & 1;
  int b = pt >> 8, rem = pt & 255;
  int h0 = rem >> 1, w0 = (rem & 1) << 7;
  int tid = threadIdx.x;
  int lane = tid & 63, wid = tid >> 6;
  int lo32 = lane & 31, hi2 = lane >> 5;

  __shared__ uint4 Ubuf[2][1600];   // 1560 used slots (+pad) per buffer

  // staging sources; LDS slot L = (r*4+sl)*130 + px  (rows of 64 slots per STG)
  const char* gsrc[7];
  #pragma unroll
  for (int i = 0; i < 7; ++i) {
    int row = (i < 6) ? (wid + 4 * i) : 24;
    int L = row * 64 + lane;
    int rsl = L / 130, px = L - rsl * 130;
    int r = rsl >> 2, sl = rsl & 3;          // r==3 only for pad slots (U over-alloc'd)
    gsrc[i] = (const char*)U +
        (size_t)(((b * HP + h0 + r) * WPAD + (w0 + px)) * CIN + sl * 8) * 2;
  }

  f32x16 acc[2][4];
  const f32x16 vz = {0.f,0.f,0.f,0.f,0.f,0.f,0.f,0.f,0.f,0.f,0.f,0.f,0.f,0.f,0.f,0.f};
  #pragma unroll
  for (int i = 0; i < 2; ++i)
    #pragma unroll
    for (int j = 0; j < 4; ++j) acc[i][j] = vz;

  // A stream: sequential 4 KB per (cc,tap); each wave owns vfgrp = mt*4 + wid
  int vfgrp = mt * 4 + wid;
  const char* aptr = Wp + (size_t)vfgrp * 294912 + lane * 16;

  int pbase = hi2 * 2080 + lo32 * 16;       // per-lane B base; rest is compile-time imm

  const char* lbuf = (const char*)&Ubuf[0][0];
  char* stb = (char*)&Ubuf[1][0];

  // prologue: stage buffer 0 (cc=0), then A(0)
  {
    char* stb0 = (char*)&Ubuf[0][0];
    char* stbw0 = stb0 + wid * 1024;
    #pragma unroll
    for (int i = 0; i < 7; ++i) {
      __builtin_amdgcn_global_load_lds((const AS1 unsigned int*)gsrc[i],
          (AS3 unsigned int*)(i < 6 ? (stbw0 + i * 4096) : (stb0 + 24576)), 16, 0, 0);
      gsrc[i] += 64;
    }
  }
  short8 afr0[4], afr1[4], bfr0[4], bfr1[4];
  afr0[0] = *(const short8*)(aptr);
  afr0[1] = *(const short8*)(aptr + 1024);
  afr0[2] = *(const short8*)(aptr + 2048);
  afr0[3] = *(const short8*)(aptr + 3072);
  WAITV(4, 0);                      // 7 stage rows done; A(0) may stay in flight
  __builtin_amdgcn_s_barrier();

  #pragma unroll 1
  for (int cc = 0; cc < 7; ++cc) {
    char* stbw = stb + wid * 1024;
    LOADB(0, 0, 0);
    // t=0: force A(0)@prev done; allow {A(1)x4, STG0}
    LOADA(1); STG(0); LOADB(1, 0, 1); WAITV(5, 4); MM(0, 0, 0);
              LOADB(0, 1, 0);        WAITL(4);     MM(0, 1, 1);
    // t=1..6: force A(t)@prev done; allow {STG(t-1), A(t+1)x4, STG(t)} -> 2-tap STG window
    LOADA(0); STG(1); LOADB(1, 1, 1); WAITV(6, 4); MM(1, 0, 0);
              LOADB(0, 2, 0);        WAITL(4);     MM(1, 1, 1);
    LOADA(1); STG(2); LOADB(1, 2, 1); WAITV(6, 4); MM(0, 0, 0);
              LOADB(0, 3, 0);        WAITL(4);     MM(0, 1, 1);
    LOADA(0); STG(3); LOADB(1, 3, 1); WAITV(6, 4); MM(1, 0, 0);
              LOADB(0, 4, 0);        WAITL(4);     MM(1, 1, 1);
    LOADA(1); STG(4); LOADB(1, 4, 1); WAITV(6, 4); MM(0, 0, 0);
              LOADB(0, 5, 0);        WAITL(4);     MM(0, 1, 1);
    LOADA(0); STG(5); LOADB(1, 5, 1); WAITV(6, 4); MM(1, 0, 0);
              LOADB(0, 6, 0);        WAITL(4);     MM(1, 1, 1);
    LOADA(1); STG(6); LOADB(1, 6, 1); WAITV(6, 4); MM(0, 0, 0);
              LOADB(0, 7, 0);        WAITL(4);     MM(0, 1, 1);
    // t=7: no STG; allow {STG6, A(8)x4}
    LOADA(0);         LOADB(1, 7, 1); WAITV(5, 4); MM(1, 0, 0);
              LOADB(0, 8, 0);        WAITL(4);     MM(1, 1, 1);
    // t=8: prefetch next cc's A(0); vm(4) forces A(8) + all STGs done pre-barrier
    LOADA(1);         LOADB(1, 8, 1); WAITV(4, 4); MM(0, 0, 0);
                                     WAITV(4, 0);  MM(0, 1, 1);
    __builtin_amdgcn_s_barrier();
    { const char* tmp = lbuf; lbuf = (const char*)stb; stb = (char*)tmp; }
    { short8 t0 = afr1[0]; afr0[0] = t0; t0 = afr1[1]; afr0[1] = t0;
      t0 = afr1[2]; afr0[2] = t0; t0 = afr1[3]; afr0[3] = t0; }
  }
  // peeled cc = 7 (no staging, no barrier)
  {
    LOADB(0, 0, 0);
    LOADA(1); LOADB(1, 0, 1); WAITV(4, 4); MM(0, 0, 0);
              LOADB(0, 1, 0); WAITL(4);    MM(0, 1, 1);
    LOADA(0); LOADB(1, 1, 1); WAITV(4, 4); MM(1, 0, 0);
              LOADB(0, 2, 0); WAITL(4);    MM(1, 1, 1);
    LOADA(1); LOADB(1, 2, 1); WAITV(4, 4); MM(0, 0, 0);
              LOADB(0, 3, 0); WAITL(4);    MM(0, 1, 1);
    LOADA(0); LOADB(1, 3, 1); WAITV(4, 4); MM(1, 0, 0);
              LOADB(0, 4, 0); WAITL(4);    MM(1, 1, 1);
    LOADA(1); LOADB(1, 4, 1); WAITV(4, 4); MM(0, 0, 0);
              LOADB(0, 5, 0); WAITL(4);    MM(0, 1, 1);
    LOADA(0); LOADB(1, 5, 1); WAITV(4, 4); MM(1, 0, 0);
              LOADB(0, 6, 0); WAITL(4);    MM(1, 1, 1);
    LOADA(1); LOADB(1, 6, 1); WAITV(4, 4); MM(0, 0, 0);
              LOADB(0, 7, 0); WAITL(4);    MM(0, 1, 1);
    LOADA(0); LOADB(1, 7, 1); WAITV(4, 4); MM(1, 0, 0);
              LOADB(0, 8, 0); WAITL(4);    MM(1, 1, 1);
              LOADB(1, 8, 1); WAITV(0, 4); MM(0, 0, 0);
                              WAITL(0);    MM(0, 1, 1);
  }

  // epilogue. C/D (32x32): col=lane&31, row=(reg&3)+8*(reg>>2)+4*(lane>>5).
  // reg=2t+g: v = mt*256+wid*64+mf*32+row -> c = cbase + (t&1) + 4*(t>>1) + 2*hi2, g=reg&1.
  #pragma unroll
  for (int mf = 0; mf < 2; ++mf) {
    int cbase = mt * 128 + wid * 32 + mf * 16;
    #pragma unroll
    for (int t = 0; t < 8; ++t) {
      int c = cbase + (t & 1) + 4 * (t >> 1) + (hi2 << 1);
      float bg = bias[c], bb = bias[256 + c];
      float mean = stats[b * 256 + c], rs = stats[1024 + b * 256 + c];
      const float* xrow = x + ((size_t)(b * 256 + c) * 128 + h0) * 256 + w0;
      float* orow = out + ((size_t)(b * 256 + c) * 128 + h0) * 256 + w0;
      #pragma unroll
      for (int nf = 0; nf < 4; ++nf) {
        int pix = nf * 32 + lo32;
        float g  = acc[mf][nf][2 * t]     + bg;
        float bt = acc[mf][nf][2 * t + 1] + bb;
        float xv = xrow[pix];
        orow[pix] = (xv - mean) * rs * (1.f + g) + bt;
      }
    }
  }
}

extern "C" void kernel_launch(void* const* d_in, const int* in_sizes, int n_in,
                              void* d_out, int out_size, void* d_ws, size_t ws_size,
                              hipStream_t stream)
{
  const float* x    = (const float*)d_in[0];
  const int*   seg  = (const int*)d_in[1];
  const float* sty  = (const float*)d_in[2];
  const float* fcw  = (const float*)d_in[3];
  const float* fcb  = (const float*)d_in[4];
  const float* cgw  = (const float*)d_in[5];
  const float* cgb  = (const float*)d_in[6];
  const float* cbw  = (const float*)d_in[7];
  const float* cbb  = (const float*)d_in[8];
  const float* mlpw = (const float*)d_in[9];
  const float* mlpb = (const float*)d_in[10];
  const float* sgw  = (const float*)d_in[11];
  const float* sgb  = (const float*)d_in[12];
  const float* sbw  = (const float*)d_in[13];
  const float* sbb  = (const float*)d_in[14];
  const float* blg  = (const float*)d_in[15];
  const float* blb  = (const float*)d_in[16];
  float* out = (float*)d_out;

  char* ws = (char*)d_ws;
  const size_t U_BYTES = (size_t)4 * HP * WPAD * CIN * 2;   // 68,689,920
  size_t off = 0;
  unsigned short* U = (unsigned short*)(ws + off); off += U_BYTES + 262144;  // pad: r==3 overshoot reads
  char* Wp   = ws + off;           off += (size_t)512 * 256 * 9 * 2;  // 2,359,296
  float* mu  = (float*)(ws + off); off += (size_t)4 * 35 * 128 * 4;   // 71,680
  float* mlpT= (float*)(ws + off); off += (size_t)35 * 9 * 128 * 4;   // 161,280
  float* bias= (float*)(ws + off); off += 2048;
  float* stats=(float*)(ws + off); off += 8192;
  if (ws_size < off) return;

  k_halo <<<dim3(387),     dim3(256), 0, stream>>>((uint4*)U);
  k_mu   <<<dim3(140),     dim3(128), 0, stream>>>(sty, fcw, fcb, mu);
  k_prep <<<dim3(158),     dim3(256), 0, stream>>>(mlpw, mlpT, cgb, cbb, sgb, sbb, blg, blb, bias);
  k_pack <<<dim3(576),     dim3(256), 0, stream>>>(cgw, cbw, sgw, sbw, blg, blb, (unsigned short*)Wp);
  k_stats<<<dim3(1024),    dim3(256), 0, stream>>>(x, stats);
  k_build<<<dim3(16384),   dim3(256), 0, stream>>>(seg, mu, mlpT, mlpb, U);
  k_conv <<<dim3(2048),    dim3(256), 0, stream>>>(x, (const uint4*)U, Wp, bias, stats, out);
}

// Round 9
// 323.787 us; speedup vs baseline: 1.1855x; 1.1855x over previous
//
#include <hip/hip_runtime.h>
#include <stdint.h>

typedef __attribute__((ext_vector_type(8))) short short8;
typedef __attribute__((ext_vector_type(4))) float f32x4;

#define HP 130
#define WPAD 258
#define CIN 256

#define AS1 __attribute__((address_space(1)))
#define AS3 __attribute__((address_space(3)))

__device__ __forceinline__ unsigned short f2bf(float f) {
  unsigned int x = __float_as_uint(f);
  x = x + 0x7fffu + ((x >> 16) & 1u);
  return (unsigned short)(x >> 16);
}

// ================= Stage A: halo-zero | mu-FC | mlpT+bias | weight-pack =================
// Blocks:   [0,387) halo   [387,527) mu   [527,685) prep   [685,1261) pack
// All four sub-tasks are mutually independent; fused to overlap + cut launch gaps.
__global__ __launch_bounds__(256) void k_stageA(
    uint4* __restrict__ U4,
    const float* __restrict__ sty, const float* __restrict__ fcw,
    const float* __restrict__ fcb, float* __restrict__ mu,
    const float* __restrict__ mlpw, float* __restrict__ mlpT,
    const float* __restrict__ cgb, const float* __restrict__ cbb,
    const float* __restrict__ sgb, const float* __restrict__ sbb,
    const float* __restrict__ blg, const float* __restrict__ blb,
    float* __restrict__ bias,
    const float* __restrict__ cgw, const float* __restrict__ cbw,
    const float* __restrict__ sgw, const float* __restrict__ sbw,
    unsigned short* __restrict__ Wp)
{
  int bid = blockIdx.x, tid = threadIdx.x;
  if (bid < 387) {
    // ---- halo: zero the pad ring of U (interior rewritten by Stage B build) ----
    int t = bid * 256 + tid;
    if (t >= 98816) return;               // 3088 halo pixels * 32 uint4
    int sub = t & 31, pi = t >> 5;
    int b = pi / 772, r = pi - b * 772;
    int h, w;
    if (r < 258)      { h = 0;   w = r; }
    else if (r < 516) { h = 129; w = r - 258; }
    else if (r < 644) { h = r - 516 + 1; w = 0; }
    else              { h = r - 644 + 1; w = 257; }
    U4[((size_t)(b * HP + h) * WPAD + w) * 32 + sub] = (uint4){0, 0, 0, 0};
  } else if (bid < 527) {
    // ---- mu[b,j,o] = relu(fc_w[j] @ style[b,j] + fc_b[j]) ----
    int bj = bid - 387;                   // 0..139
    int b = bj / 35, j = bj - 35 * b;
    __shared__ float ss[128];
    if (tid < 128) ss[tid] = sty[((size_t)b * 35 + j) * 128 + tid];
    __syncthreads();
    if (tid < 128) {
      int o = tid;
      const float4* wr = (const float4*)(fcw + ((size_t)j * 128 + o) * 128);
      const float4* sv = (const float4*)ss;
      float acc = fcb[j * 128 + o];
      #pragma unroll 8
      for (int d = 0; d < 32; ++d) {
        float4 wv = wr[d], s4 = sv[d];
        acc += wv.x * s4.x + wv.y * s4.y + wv.z * s4.z + wv.w * s4.w;
      }
      mu[((size_t)b * 35 + j) * 128 + o] = fmaxf(acc, 0.f);
    }
  } else if (bid < 685) {
    // ---- mlpT transpose + blended biases ----
    int t = (bid - 527) * 256 + tid;
    if (t < 40320) {
      int o = t & 127;
      int jt = t >> 7;                    // j*9 + tap
      mlpT[(size_t)jt * 128 + o] = mlpw[((size_t)o * 35 + (jt / 9)) * 9 + (jt % 9)];
    }
    if (t < 256) {
      float ga = 1.f / (1.f + expf(-blg[0]));
      float ba = 1.f / (1.f + expf(-blb[0]));
      bias[t]       = ga * cgb[t] + (1.f - ga) * sgb[t];
      bias[256 + t] = ba * cbb[t] + (1.f - ba) * sbb[t];
    }
  } else {
    // ---- packed, blended bf16 weights: [vfgrp(8)][cc(8)][tap(9)][mf(4)][lane(64)] x16B
    // vf = vfgrp*4+mf; v = vf*16+(lane&15); k-index = cc*32 + 8*(lane>>4) + j
    int gid = (bid - 685) * 256 + tid;    // 147456 exactly
    int lane = gid & 63;
    int cc = (gid >> 6) & 7;
    int rest = gid >> 9;                  // vf*9 + tap
    int tap = rest % 9;
    int vf = rest / 9;
    int v = vf * 16 + (lane & 15);
    int c = v >> 1, g = v & 1;
    int ci0 = cc * 32 + (lane >> 4) * 8;
    float ga = 1.f / (1.f + expf(-blg[0]));
    float ba = 1.f / (1.f + expf(-blb[0]));
    float sc = g ? ba : ga;
    const float* wavg = g ? cbw : cgw;
    const float* wsp  = g ? sbw : sgw;
    union { uint4 v4; unsigned short s[8]; } u;
    #pragma unroll
    for (int jj = 0; jj < 8; ++jj) {
      int ci = ci0 + jj;
      float val;
      if (ci < 128) val = sc * wavg[((size_t)c * 128 + ci) * 9 + tap];
      else          val = (1.f - sc) * wsp[((size_t)c * 128 + (ci - 128)) * 9 + tap];
      u.s[jj] = f2bf(val);
    }
    int vfgrp = vf >> 2, mfi = vf & 3;
    uint4* dst = (uint4*)Wp + ((size_t)(((vfgrp * 8 + cc) * 9 + tap) * 4 + mfi)) * 64 + lane;
    *dst = u.v4;
  }
}

// ================= Stage B: IN-stats | build U  (independent; fused to overlap) =========
// Blocks: [0,1024) stats   [1024,17408) build
__global__ __launch_bounds__(256) void k_stageB(
    const float* __restrict__ x, float* __restrict__ stats,
    const int* __restrict__ seg, const float* __restrict__ mu,
    const float* __restrict__ mlpT, const float* __restrict__ mlpb,
    unsigned short* __restrict__ U)
{
  int bid = blockIdx.x, t = threadIdx.x;
  if (bid < 1024) {
    // ---- instance-norm stats: mean + rstd per (b,c) ----
    int bc = bid;
    const float* p = x + (size_t)bc * 32768;
    float s = 0.f, s2 = 0.f;
    #pragma unroll 4
    for (int i = 0; i < 32; ++i) {
      float4 v = *(const float4*)(p + (size_t)i * 1024 + t * 4);
      s  += v.x + v.y + v.z + v.w;
      s2 += v.x * v.x + v.y * v.y + v.z * v.z + v.w * v.w;
    }
    #pragma unroll
    for (int off2 = 32; off2 > 0; off2 >>= 1) {
      s  += __shfl_down(s, off2);
      s2 += __shfl_down(s2, off2);
    }
    __shared__ float red[8];
    int lane = t & 63, wv = t >> 6;
    if (lane == 0) { red[wv] = s; red[4 + wv] = s2; }
    __syncthreads();
    if (t == 0) {
      float S  = red[0] + red[1] + red[2] + red[3];
      float S2 = red[4] + red[5] + red[6] + red[7];
      float mean = S * (1.f / 32768.f);
      float var  = S2 * (1.f / 32768.f) - mean * mean;
      stats[bc] = mean;
      stats[1024 + bc] = rsqrtf(var + 1e-5f);
    }
  } else {
    // ---- build padded channel-last bf16 input U[b][h+1][w+1][256] ----
    int blk = bid - 1024;               // 16384
    int b = blk >> 12, rem = blk & 4095;
    int h = rem >> 5, w0 = (rem & 31) << 3;
    int p = t >> 5, q = t & 31;
    int w = w0 + p;
    unsigned short* up = U + (((size_t)(b * HP + h + 1)) * WPAD + (w + 1)) * CIN;
    union { uint4 v4; unsigned short s[8]; } u;
    if (q < 16) {
      int lab = seg[((size_t)b * 128 + h) * 256 + w];
      const float4* mrow = (const float4*)(mu + ((size_t)(b * 35 + lab)) * 128 + q * 8);
      float4 v0 = mrow[0], v1 = mrow[1];
      u.s[0] = f2bf(v0.x); u.s[1] = f2bf(v0.y); u.s[2] = f2bf(v0.z); u.s[3] = f2bf(v0.w);
      u.s[4] = f2bf(v1.x); u.s[5] = f2bf(v1.y); u.s[6] = f2bf(v1.z); u.s[7] = f2bf(v1.w);
      *(uint4*)(up + q * 8) = u.v4;
    } else {
      int o0 = (q - 16) * 8;
      float a[8];
      #pragma unroll
      for (int j = 0; j < 8; ++j) a[j] = mlpb[o0 + j];
      #pragma unroll
      for (int kh = 0; kh < 3; ++kh) {
        int hh = h + kh - 1;
        if ((unsigned)hh < 128u) {
          #pragma unroll
          for (int kw = 0; kw < 3; ++kw) {
            int ww = w + kw - 1;
            if ((unsigned)ww < 256u) {
              int lab2 = seg[((size_t)b * 128 + hh) * 256 + ww];
              const float4* wr = (const float4*)(mlpT + ((size_t)lab2 * 9 + kh * 3 + kw) * 128 + o0);
              float4 v0 = wr[0], v1 = wr[1];
              a[0] += v0.x; a[1] += v0.y; a[2] += v0.z; a[3] += v0.w;
              a[4] += v1.x; a[5] += v1.y; a[6] += v1.z; a[7] += v1.w;
            }
          }
        }
      }
      #pragma unroll
      for (int j = 0; j < 8; ++j) u.s[j] = f2bf(fmaxf(a[j], 0.f));
      *(uint4*)(up + 128 + o0) = u.v4;
    }
  }
}

// ---------------- main fused conv: 4 waves x (64v x 128px) = 256v x 128px per block ----
// (R7 version, verbatim — best measured: 260 µs, MfmaUtil 55%.)
// Counted vmcnt: per-tap waits allow {STG(t-1), A(t)x4, STG(t)} outstanding -> every
// HBM staging load gets a >=2-tap (~1200 cyc) completion window; never drains mid-loop.
// __launch_bounds__(256,2): acc(128 AGPR) + arch(128) = full 256/wave; (256,3) spills (R6).

#define WAITV_(vm, lg) asm volatile("s_waitcnt vmcnt(" #vm ") lgkmcnt(" #lg ")" ::: "memory")
#define WAITV(vm, lg) do { WAITV_(vm, lg); __builtin_amdgcn_sched_barrier(0); } while (0)
#define WAITL(lg) do { asm volatile("s_waitcnt lgkmcnt(" #lg ")" ::: "memory"); __builtin_amdgcn_sched_barrier(0); } while (0)

#define MM(AS, BS, H) do {                                                     \
    __builtin_amdgcn_s_setprio(1);                                             \
    _Pragma("unroll")                                                          \
    for (int mf_ = 0; mf_ < 4; ++mf_)                                          \
      _Pragma("unroll")                                                        \
      for (int nf_ = 0; nf_ < 4; ++nf_)                                        \
        acc[mf_][(H) * 4 + nf_] = __builtin_amdgcn_mfma_f32_16x16x32_bf16(     \
            afr##AS[mf_], bfr##BS[nf_], acc[mf_][(H) * 4 + nf_], 0, 0, 0);     \
    __builtin_amdgcn_s_setprio(0);                                             \
  } while (0)

#define LOADA(NS) do {                                                         \
    aptr += 4096;                                                              \
    afr##NS[0] = *(const short8*)(aptr);                                       \
    afr##NS[1] = *(const short8*)(aptr + 1024);                                \
    afr##NS[2] = *(const short8*)(aptr + 2048);                                \
    afr##NS[3] = *(const short8*)(aptr + 3072);                                \
  } while (0)

#define LOADB(NS, T, H) do {                                                   \
    bfr##NS[0] = *(const short8*)(lbuf + off[T] + (H) * 4096);                 \
    bfr##NS[1] = *(const short8*)(lbuf + off[T] + (H) * 4096 + 1024);          \
    bfr##NS[2] = *(const short8*)(lbuf + off[T] + (H) * 4096 + 2048);          \
    bfr##NS[3] = *(const short8*)(lbuf + off[T] + (H) * 4096 + 3072);          \
  } while (0)

#define STG(SI) do {                                                           \
    __builtin_amdgcn_global_load_lds((const AS1 unsigned int*)gsrc[SI],        \
        (AS3 unsigned int*)((SI) < 6 ? (stbw + (SI) * 4096) : (stb + 24576)),  \
        16, 0, 0);                                                             \
    gsrc[SI] += 64;                                                            \
  } while (0)

__global__ __launch_bounds__(256, 2) void k_conv(
    const float* __restrict__ x, const uint4* __restrict__ U,
    const char* __restrict__ Wp, const float* __restrict__ bias,
    const float* __restrict__ stats, float* __restrict__ out)
{
  int bid = blockIdx.x;                // 2048
  int xcd = bid & 7, i0 = bid >> 3;    // i0: 0..255
  int pt = xcd * 128 + (i0 >> 1);      // mt fastest within an XCD
  int mt = i0 & 1;
  int b = pt >> 8, rem = pt & 255;
  int h0 = rem >> 1, w0 = (rem & 1) << 7;
  int tid = threadIdx.x;
  int lane = tid & 63, wid = tid >> 6;
  int lo = lane & 15, hi = lane >> 4;

  __shared__ uint4 Ubuf[2][1600];   // 25 rows of 1 KB (+pad) per buffer

  // staging source addresses; row_i = (i<6) ? wid+4*i : 24 (row 24 issued by ALL waves)
  const char* gsrc[7];
  #pragma unroll
  for (int i = 0; i < 7; ++i) {
    int row = (i < 6) ? (wid + 4 * i) : 24;
    int slot = row * 64 + lane;
    int P = slot >> 2, sp = slot & 3;
    int sl = sp ^ ((P >> 1) & 3);
    int r = P / 130, pix = P - r * 130;     // r==3 only for row-24 pad lanes (U over-alloc'd)
    gsrc[i] = (const char*)U +
        (size_t)(((b * HP + h0 + r) * WPAD + (w0 + pix)) * CIN + sl * 8) * 2;
  }

  f32x4 acc[4][8];
  #pragma unroll
  for (int i = 0; i < 4; ++i)
    #pragma unroll
    for (int j = 0; j < 8; ++j) acc[i][j] = (f32x4){0.f, 0.f, 0.f, 0.f};

  // A stream: sequential 4 KB per (cc,tap); each wave owns vfgrp = mt*4 + wid
  int vfgrp = mt * 4 + wid;
  const char* aptr = Wp + (size_t)vfgrp * 294912 + lane * 16;

  // B read offsets per tap (pixel base = lo; nf adds 1024 B; swizzle invariant in nf)
  int off[9];
  #pragma unroll
  for (int t = 0; t < 9; ++t) {
    int Pb = (t / 3) * 130 + (t % 3) + lo;
    off[t] = Pb * 64 + ((hi ^ ((Pb >> 1) & 3)) << 4);
  }

  const char* lbuf = (const char*)&Ubuf[0][0];
  char* stb = (char*)&Ubuf[1][0];

  // prologue: stage buffer 0 (cc=0), then A(0)
  {
    char* stb0 = (char*)&Ubuf[0][0];
    char* stbw0 = stb0 + wid * 1024;
    #pragma unroll
    for (int i = 0; i < 7; ++i) {
      __builtin_amdgcn_global_load_lds((const AS1 unsigned int*)gsrc[i],
          (AS3 unsigned int*)(i < 6 ? (stbw0 + i * 4096) : (stb0 + 24576)), 16, 0, 0);
      gsrc[i] += 64;
    }
  }
  short8 afr0[4], afr1[4], bfr0[4], bfr1[4];
  afr0[0] = *(const short8*)(aptr);
  afr0[1] = *(const short8*)(aptr + 1024);
  afr0[2] = *(const short8*)(aptr + 2048);
  afr0[3] = *(const short8*)(aptr + 3072);
  WAITV(4, 0);                      // 7 stage rows done; A(0) may stay in flight
  __builtin_amdgcn_s_barrier();

  #pragma unroll 1
  for (int cc = 0; cc < 7; ++cc) {
    char* stbw = stb + wid * 1024;
    LOADB(0, 0, 0);
    // t=0: force A(0)@prev done; allow {A(1)x4, STG0}
    LOADA(1); STG(0); LOADB(1, 0, 1); WAITV(5, 4); MM(0, 0, 0);
              LOADB(0, 1, 0);        WAITL(4);     MM(0, 1, 1);
    // t=1..6: force A(t)@prev done; allow {STG(t-1), A(t+1)x4, STG(t)} -> 2-tap STG window
    LOADA(0); STG(1); LOADB(1, 1, 1); WAITV(6, 4); MM(1, 0, 0);
              LOADB(0, 2, 0);        WAITL(4);     MM(1, 1, 1);
    LOADA(1); STG(2); LOADB(1, 2, 1); WAITV(6, 4); MM(0, 0, 0);
              LOADB(0, 3, 0);        WAITL(4);     MM(0, 1, 1);
    LOADA(0); STG(3); LOADB(1, 3, 1); WAITV(6, 4); MM(1, 0, 0);
              LOADB(0, 4, 0);        WAITL(4);     MM(1, 1, 1);
    LOADA(1); STG(4); LOADB(1, 4, 1); WAITV(6, 4); MM(0, 0, 0);
              LOADB(0, 5, 0);        WAITL(4);     MM(0, 1, 1);
    LOADA(0); STG(5); LOADB(1, 5, 1); WAITV(6, 4); MM(1, 0, 0);
              LOADB(0, 6, 0);        WAITL(4);     MM(1, 1, 1);
    LOADA(1); STG(6); LOADB(1, 6, 1); WAITV(6, 4); MM(0, 0, 0);
              LOADB(0, 7, 0);        WAITL(4);     MM(0, 1, 1);
    // t=7: no STG; allow {STG6, A(8)x4}
    LOADA(0);         LOADB(1, 7, 1); WAITV(5, 4); MM(1, 0, 0);
              LOADB(0, 8, 0);        WAITL(4);     MM(1, 1, 1);
    // t=8: prefetch next cc's A(0); vm(4) forces A(8) + all STGs done pre-barrier
    LOADA(1);         LOADB(1, 8, 1); WAITV(4, 4); MM(0, 0, 0);
                                     WAITV(4, 0);  MM(0, 1, 1);
    __builtin_amdgcn_s_barrier();
    { const char* tmp = lbuf; lbuf = (const char*)stb; stb = (char*)tmp; }
    { short8 t0 = afr1[0]; afr0[0] = t0; t0 = afr1[1]; afr0[1] = t0;
      t0 = afr1[2]; afr0[2] = t0; t0 = afr1[3]; afr0[3] = t0; }
  }
  // peeled cc = 7 (no staging, no barrier)
  {
    LOADB(0, 0, 0);
    LOADA(1); LOADB(1, 0, 1); WAITV(4, 4); MM(0, 0, 0);
              LOADB(0, 1, 0); WAITL(4);    MM(0, 1, 1);
    LOADA(0); LOADB(1, 1, 1); WAITV(4, 4); MM(1, 0, 0);
              LOADB(0, 2, 0); WAITL(4);    MM(1, 1, 1);
    LOADA(1); LOADB(1, 2, 1); WAITV(4, 4); MM(0, 0, 0);
              LOADB(0, 3, 0); WAITL(4);    MM(0, 1, 1);
    LOADA(0); LOADB(1, 3, 1); WAITV(4, 4); MM(1, 0, 0);
              LOADB(0, 4, 0); WAITL(4);    MM(1, 1, 1);
    LOADA(1); LOADB(1, 4, 1); WAITV(4, 4); MM(0, 0, 0);
              LOADB(0, 5, 0); WAITL(4);    MM(0, 1, 1);
    LOADA(0); LOADB(1, 5, 1); WAITV(4, 4); MM(1, 0, 0);
              LOADB(0, 6, 0); WAITL(4);    MM(1, 1, 1);
    LOADA(1); LOADB(1, 6, 1); WAITV(4, 4); MM(0, 0, 0);
              LOADB(0, 7, 0); WAITL(4);    MM(0, 1, 1);
    LOADA(0); LOADB(1, 7, 1); WAITV(4, 4); MM(1, 0, 0);
              LOADB(0, 8, 0); WAITL(4);    MM(1, 1, 1);
              LOADB(1, 8, 1); WAITV(0, 4); MM(0, 0, 0);
                              WAITL(0);    MM(0, 1, 1);
  }

  // epilogue: bias + instance-norm + blend; C/D: col=lane&15, row=(lane>>4)*4+reg
  #pragma unroll
  for (int mf = 0; mf < 4; ++mf) {
    int vbase = mt * 256 + wid * 64 + mf * 16 + hi * 4;
    #pragma unroll
    for (int p = 0; p < 2; ++p) {
      int c = (vbase >> 1) + p;
      float bg = bias[c], bb = bias[256 + c];
      float mean = stats[b * 256 + c], rs = stats[1024 + b * 256 + c];
      const float* xrow = x + ((size_t)(b * 256 + c) * 128 + h0) * 256 + w0;
      float* orow = out + ((size_t)(b * 256 + c) * 128 + h0) * 256 + w0;
      #pragma unroll
      for (int nf = 0; nf < 8; ++nf) {
        int pix = nf * 16 + lo;
        float g  = acc[mf][nf][2 * p]     + bg;
        float bt = acc[mf][nf][2 * p + 1] + bb;
        float xv = xrow[pix];
        orow[pix] = (xv - mean) * rs * (1.f + g) + bt;
      }
    }
  }
}

extern "C" void kernel_launch(void* const* d_in, const int* in_sizes, int n_in,
                              void* d_out, int out_size, void* d_ws, size_t ws_size,
                              hipStream_t stream)
{
  const float* x    = (const float*)d_in[0];
  const int*   seg  = (const int*)d_in[1];
  const float* sty  = (const float*)d_in[2];
  const float* fcw  = (const float*)d_in[3];
  const float* fcb  = (const float*)d_in[4];
  const float* cgw  = (const float*)d_in[5];
  const float* cgb  = (const float*)d_in[6];
  const float* cbw  = (const float*)d_in[7];
  const float* cbb  = (const float*)d_in[8];
  const float* mlpw = (const float*)d_in[9];
  const float* mlpb = (const float*)d_in[10];
  const float* sgw  = (const float*)d_in[11];
  const float* sgb  = (const float*)d_in[12];
  const float* sbw  = (const float*)d_in[13];
  const float* sbb  = (const float*)d_in[14];
  const float* blg  = (const float*)d_in[15];
  const float* blb  = (const float*)d_in[16];
  float* out = (float*)d_out;

  char* ws = (char*)d_ws;
  const size_t U_BYTES = (size_t)4 * HP * WPAD * CIN * 2;   // 68,689,920
  size_t off = 0;
  unsigned short* U = (unsigned short*)(ws + off); off += U_BYTES + 262144;  // pad: row-24 overshoot reads
  char* Wp   = ws + off;           off += (size_t)512 * 256 * 9 * 2;  // 2,359,296
  float* mu  = (float*)(ws + off); off += (size_t)4 * 35 * 128 * 4;   // 71,680
  float* mlpT= (float*)(ws + off); off += (size_t)35 * 9 * 128 * 4;   // 161,280
  float* bias= (float*)(ws + off); off += 2048;
  float* stats=(float*)(ws + off); off += 8192;
  if (ws_size < off) return;

  k_stageA<<<dim3(1261),  dim3(256), 0, stream>>>((uint4*)U,
      sty, fcw, fcb, mu, mlpw, mlpT, cgb, cbb, sgb, sbb, blg, blb, bias,
      cgw, cbw, sgw, sbw, (unsigned short*)Wp);
  k_stageB<<<dim3(17408), dim3(256), 0, stream>>>(x, stats, seg, mu, mlpT, mlpb, U);
  k_conv  <<<dim3(2048),  dim3(256), 0, stream>>>(x, (const uint4*)U, Wp, bias, stats, out);
}

// Round 10
// 323.293 us; speedup vs baseline: 1.1873x; 1.0015x over previous
//
#include <hip/hip_runtime.h>
#include <stdint.h>

typedef __attribute__((ext_vector_type(8))) short short8;
typedef __attribute__((ext_vector_type(4))) float f32x4;

#define HP 130
#define WPAD 258
#define CIN 256

#define AS1 __attribute__((address_space(1)))
#define AS3 __attribute__((address_space(3)))

__device__ __forceinline__ unsigned short f2bf(float f) {
  unsigned int x = __float_as_uint(f);
  x = x + 0x7fffu + ((x >> 16) & 1u);
  return (unsigned short)(x >> 16);
}

// ================= k1: mu-FC | mlpT+bias  (only true upstream deps of build) ===========
// Blocks: [0,140) mu   [140,298) prep
__global__ __launch_bounds__(256) void k_pre(
    const float* __restrict__ sty, const float* __restrict__ fcw,
    const float* __restrict__ fcb, float* __restrict__ mu,
    const float* __restrict__ mlpw, float* __restrict__ mlpT,
    const float* __restrict__ cgb, const float* __restrict__ cbb,
    const float* __restrict__ sgb, const float* __restrict__ sbb,
    const float* __restrict__ blg, const float* __restrict__ blb,
    float* __restrict__ bias)
{
  int bid = blockIdx.x, tid = threadIdx.x;
  if (bid < 140) {
    // ---- mu[b,j,o] = relu(fc_w[j] @ style[b,j] + fc_b[j]) ----
    int b = bid / 35, j = bid - 35 * b;
    __shared__ float ss[128];
    if (tid < 128) ss[tid] = sty[((size_t)b * 35 + j) * 128 + tid];
    __syncthreads();
    if (tid < 128) {
      int o = tid;
      const float4* wr = (const float4*)(fcw + ((size_t)j * 128 + o) * 128);
      const float4* sv = (const float4*)ss;
      float acc = fcb[j * 128 + o];
      #pragma unroll 8
      for (int d = 0; d < 32; ++d) {
        float4 wv = wr[d], s4 = sv[d];
        acc += wv.x * s4.x + wv.y * s4.y + wv.z * s4.z + wv.w * s4.w;
      }
      mu[((size_t)b * 35 + j) * 128 + o] = fmaxf(acc, 0.f);
    }
  } else {
    // ---- mlpT transpose + blended biases ----
    int t = (bid - 140) * 256 + tid;
    if (t < 40320) {
      int o = t & 127;
      int jt = t >> 7;                    // j*9 + tap
      mlpT[(size_t)jt * 128 + o] = mlpw[((size_t)o * 35 + (jt / 9)) * 9 + (jt % 9)];
    }
    if (t < 256) {
      float ga = 1.f / (1.f + expf(-blg[0]));
      float ba = 1.f / (1.f + expf(-blb[0]));
      bias[t]       = ga * cgb[t] + (1.f - ga) * sgb[t];
      bias[256 + t] = ba * cbb[t] + (1.f - ba) * sbb[t];
    }
  }
}

// ================= k2: IN-stats | build U | halo-zero | weight-pack  (all independent) ==
// Blocks: [0,1024) stats   [1024,17408) build   [17408,17795) halo   [17795,18371) pack
// halo and build write disjoint regions of U (pad ring vs interior) -> safe in one kernel.
__global__ __launch_bounds__(256) void k_mid(
    const float* __restrict__ x, float* __restrict__ stats,
    const int* __restrict__ seg, const float* __restrict__ mu,
    const float* __restrict__ mlpT, const float* __restrict__ mlpb,
    unsigned short* __restrict__ U,
    const float* __restrict__ cgw, const float* __restrict__ cbw,
    const float* __restrict__ sgw, const float* __restrict__ sbw,
    const float* __restrict__ blg, const float* __restrict__ blb,
    unsigned short* __restrict__ Wp)
{
  int bid = blockIdx.x, t = threadIdx.x;
  if (bid < 1024) {
    // ---- instance-norm stats: mean + rstd per (b,c) ----
    int bc = bid;
    const float* p = x + (size_t)bc * 32768;
    float s = 0.f, s2 = 0.f;
    #pragma unroll 4
    for (int i = 0; i < 32; ++i) {
      float4 v = *(const float4*)(p + (size_t)i * 1024 + t * 4);
      s  += v.x + v.y + v.z + v.w;
      s2 += v.x * v.x + v.y * v.y + v.z * v.z + v.w * v.w;
    }
    #pragma unroll
    for (int off2 = 32; off2 > 0; off2 >>= 1) {
      s  += __shfl_down(s, off2);
      s2 += __shfl_down(s2, off2);
    }
    __shared__ float red[8];
    int lane = t & 63, wv = t >> 6;
    if (lane == 0) { red[wv] = s; red[4 + wv] = s2; }
    __syncthreads();
    if (t == 0) {
      float S  = red[0] + red[1] + red[2] + red[3];
      float S2 = red[4] + red[5] + red[6] + red[7];
      float mean = S * (1.f / 32768.f);
      float var  = S2 * (1.f / 32768.f) - mean * mean;
      stats[bc] = mean;
      stats[1024 + bc] = rsqrtf(var + 1e-5f);
    }
  } else if (bid < 17408) {
    // ---- build padded channel-last bf16 input U[b][h+1][w+1][256] ----
    int blk = bid - 1024;               // 16384
    int b = blk >> 12, rem = blk & 4095;
    int h = rem >> 5, w0 = (rem & 31) << 3;
    int p = t >> 5, q = t & 31;
    int w = w0 + p;
    unsigned short* up = U + (((size_t)(b * HP + h + 1)) * WPAD + (w + 1)) * CIN;
    union { uint4 v4; unsigned short s[8]; } u;
    if (q < 16) {
      int lab = seg[((size_t)b * 128 + h) * 256 + w];
      const float4* mrow = (const float4*)(mu + ((size_t)(b * 35 + lab)) * 128 + q * 8);
      float4 v0 = mrow[0], v1 = mrow[1];
      u.s[0] = f2bf(v0.x); u.s[1] = f2bf(v0.y); u.s[2] = f2bf(v0.z); u.s[3] = f2bf(v0.w);
      u.s[4] = f2bf(v1.x); u.s[5] = f2bf(v1.y); u.s[6] = f2bf(v1.z); u.s[7] = f2bf(v1.w);
      *(uint4*)(up + q * 8) = u.v4;
    } else {
      int o0 = (q - 16) * 8;
      float a[8];
      #pragma unroll
      for (int j = 0; j < 8; ++j) a[j] = mlpb[o0 + j];
      #pragma unroll
      for (int kh = 0; kh < 3; ++kh) {
        int hh = h + kh - 1;
        if ((unsigned)hh < 128u) {
          #pragma unroll
          for (int kw = 0; kw < 3; ++kw) {
            int ww = w + kw - 1;
            if ((unsigned)ww < 256u) {
              int lab2 = seg[((size_t)b * 128 + hh) * 256 + ww];
              const float4* wr = (const float4*)(mlpT + ((size_t)lab2 * 9 + kh * 3 + kw) * 128 + o0);
              float4 v0 = wr[0], v1 = wr[1];
              a[0] += v0.x; a[1] += v0.y; a[2] += v0.z; a[3] += v0.w;
              a[4] += v1.x; a[5] += v1.y; a[6] += v1.z; a[7] += v1.w;
            }
          }
        }
      }
      #pragma unroll
      for (int j = 0; j < 8; ++j) u.s[j] = f2bf(fmaxf(a[j], 0.f));
      *(uint4*)(up + 128 + o0) = u.v4;
    }
  } else if (bid < 17795) {
    // ---- halo: zero the pad ring of U (disjoint from build's interior writes) ----
    int tt = (bid - 17408) * 256 + t;
    if (tt >= 98816) return;            // 3088 halo pixels * 32 uint4
    int sub = tt & 31, pi = tt >> 5;
    int b = pi / 772, r = pi - b * 772;
    int h, w;
    if (r < 258)      { h = 0;   w = r; }
    else if (r < 516) { h = 129; w = r - 258; }
    else if (r < 644) { h = r - 516 + 1; w = 0; }
    else              { h = r - 644 + 1; w = 257; }
    ((uint4*)U)[((size_t)(b * HP + h) * WPAD + w) * 32 + sub] = (uint4){0, 0, 0, 0};
  } else {
    // ---- packed, blended bf16 weights: [vfgrp(8)][cc(8)][tap(9)][mf(4)][lane(64)] x16B
    // vf = vfgrp*4+mf; v = vf*16+(lane&15); k-index = cc*32 + 8*(lane>>4) + j
    int gid = (bid - 17795) * 256 + t;  // 147456 exactly
    int lane = gid & 63;
    int cc = (gid >> 6) & 7;
    int rest = gid >> 9;                // vf*9 + tap
    int tap = rest % 9;
    int vf = rest / 9;
    int v = vf * 16 + (lane & 15);
    int c = v >> 1, g = v & 1;
    int ci0 = cc * 32 + (lane >> 4) * 8;
    float ga = 1.f / (1.f + expf(-blg[0]));
    float ba = 1.f / (1.f + expf(-blb[0]));
    float sc = g ? ba : ga;
    const float* wavg = g ? cbw : cgw;
    const float* wsp  = g ? sbw : sgw;
    union { uint4 v4; unsigned short s[8]; } u;
    #pragma unroll
    for (int jj = 0; jj < 8; ++jj) {
      int ci = ci0 + jj;
      float val;
      if (ci < 128) val = sc * wavg[((size_t)c * 128 + ci) * 9 + tap];
      else          val = (1.f - sc) * wsp[((size_t)c * 128 + (ci - 128)) * 9 + tap];
      u.s[jj] = f2bf(val);
    }
    int vfgrp = vf >> 2, mfi = vf & 3;
    uint4* dst = (uint4*)Wp + ((size_t)(((vfgrp * 8 + cc) * 9 + tap) * 4 + mfi)) * 64 + lane;
    *dst = u.v4;
  }
}

// ---------------- main fused conv: 4 waves x (64v x 128px) = 256v x 128px per block ----
// (R7 version, verbatim — best measured: 257 µs, MfmaUtil 55%.)
// Counted vmcnt: per-tap waits allow {STG(t-1), A(t)x4, STG(t)} outstanding -> every
// HBM staging load gets a >=2-tap (~1200 cyc) completion window; never drains mid-loop.
// __launch_bounds__(256,2): acc(128 AGPR) + arch(128 VGPR) = full 256/wave; (256,3) spills (R6).

#define WAITV_(vm, lg) asm volatile("s_waitcnt vmcnt(" #vm ") lgkmcnt(" #lg ")" ::: "memory")
#define WAITV(vm, lg) do { WAITV_(vm, lg); __builtin_amdgcn_sched_barrier(0); } while (0)
#define WAITL(lg) do { asm volatile("s_waitcnt lgkmcnt(" #lg ")" ::: "memory"); __builtin_amdgcn_sched_barrier(0); } while (0)

#define MM(AS, BS, H) do {                                                     \
    __builtin_amdgcn_s_setprio(1);                                             \
    _Pragma("unroll")                                                          \
    for (int mf_ = 0; mf_ < 4; ++mf_)                                          \
      _Pragma("unroll")                                                        \
      for (int nf_ = 0; nf_ < 4; ++nf_)                                        \
        acc[mf_][(H) * 4 + nf_] = __builtin_amdgcn_mfma_f32_16x16x32_bf16(     \
            afr##AS[mf_], bfr##BS[nf_], acc[mf_][(H) * 4 + nf_], 0, 0, 0);     \
    __builtin_amdgcn_s_setprio(0);                                             \
  } while (0)

#define LOADA(NS) do {                                                         \
    aptr += 4096;                                                              \
    afr##NS[0] = *(const short8*)(aptr);                                       \
    afr##NS[1] = *(const short8*)(aptr + 1024);                                \
    afr##NS[2] = *(const short8*)(aptr + 2048);                                \
    afr##NS[3] = *(const short8*)(aptr + 3072);                                \
  } while (0)

#define LOADB(NS, T, H) do {                                                   \
    bfr##NS[0] = *(const short8*)(lbuf + off[T] + (H) * 4096);                 \
    bfr##NS[1] = *(const short8*)(lbuf + off[T] + (H) * 4096 + 1024);          \
    bfr##NS[2] = *(const short8*)(lbuf + off[T] + (H) * 4096 + 2048);          \
    bfr##NS[3] = *(const short8*)(lbuf + off[T] + (H) * 4096 + 3072);          \
  } while (0)

#define STG(SI) do {                                                           \
    __builtin_amdgcn_global_load_lds((const AS1 unsigned int*)gsrc[SI],        \
        (AS3 unsigned int*)((SI) < 6 ? (stbw + (SI) * 4096) : (stb + 24576)),  \
        16, 0, 0);                                                             \
    gsrc[SI] += 64;                                                            \
  } while (0)

__global__ __launch_bounds__(256, 2) void k_conv(
    const float* __restrict__ x, const uint4* __restrict__ U,
    const char* __restrict__ Wp, const float* __restrict__ bias,
    const float* __restrict__ stats, float* __restrict__ out)
{
  int bid = blockIdx.x;                // 2048
  int xcd = bid & 7, i0 = bid >> 3;    // i0: 0..255
  int pt = xcd * 128 + (i0 >> 1);      // mt fastest within an XCD
  int mt = i0 & 1;
  int b = pt >> 8, rem = pt & 255;
  int h0 = rem >> 1, w0 = (rem & 1) << 7;
  int tid = threadIdx.x;
  int lane = tid & 63, wid = tid >> 6;
  int lo = lane & 15, hi = lane >> 4;

  __shared__ uint4 Ubuf[2][1600];   // 25 rows of 1 KB (+pad) per buffer

  // staging source addresses; row_i = (i<6) ? wid+4*i : 24 (row 24 issued by ALL waves)
  const char* gsrc[7];
  #pragma unroll
  for (int i = 0; i < 7; ++i) {
    int row = (i < 6) ? (wid + 4 * i) : 24;
    int slot = row * 64 + lane;
    int P = slot >> 2, sp = slot & 3;
    int sl = sp ^ ((P >> 1) & 3);
    int r = P / 130, pix = P - r * 130;     // r==3 only for row-24 pad lanes (U over-alloc'd)
    gsrc[i] = (const char*)U +
        (size_t)(((b * HP + h0 + r) * WPAD + (w0 + pix)) * CIN + sl * 8) * 2;
  }

  f32x4 acc[4][8];
  #pragma unroll
  for (int i = 0; i < 4; ++i)
    #pragma unroll
    for (int j = 0; j < 8; ++j) acc[i][j] = (f32x4){0.f, 0.f, 0.f, 0.f};

  // A stream: sequential 4 KB per (cc,tap); each wave owns vfgrp = mt*4 + wid
  int vfgrp = mt * 4 + wid;
  const char* aptr = Wp + (size_t)vfgrp * 294912 + lane * 16;

  // B read offsets per tap (pixel base = lo; nf adds 1024 B; swizzle invariant in nf)
  int off[9];
  #pragma unroll
  for (int t = 0; t < 9; ++t) {
    int Pb = (t / 3) * 130 + (t % 3) + lo;
    off[t] = Pb * 64 + ((hi ^ ((Pb >> 1) & 3)) << 4);
  }

  const char* lbuf = (const char*)&Ubuf[0][0];
  char* stb = (char*)&Ubuf[1][0];

  // prologue: stage buffer 0 (cc=0), then A(0)
  {
    char* stb0 = (char*)&Ubuf[0][0];
    char* stbw0 = stb0 + wid * 1024;
    #pragma unroll
    for (int i = 0; i < 7; ++i) {
      __builtin_amdgcn_global_load_lds((const AS1 unsigned int*)gsrc[i],
          (AS3 unsigned int*)(i < 6 ? (stbw0 + i * 4096) : (stb0 + 24576)), 16, 0, 0);
      gsrc[i] += 64;
    }
  }
  short8 afr0[4], afr1[4], bfr0[4], bfr1[4];
  afr0[0] = *(const short8*)(aptr);
  afr0[1] = *(const short8*)(aptr + 1024);
  afr0[2] = *(const short8*)(aptr + 2048);
  afr0[3] = *(const short8*)(aptr + 3072);
  WAITV(4, 0);                      // 7 stage rows done; A(0) may stay in flight
  __builtin_amdgcn_s_barrier();

  #pragma unroll 1
  for (int cc = 0; cc < 7; ++cc) {
    char* stbw = stb + wid * 1024;
    LOADB(0, 0, 0);
    // t=0: force A(0)@prev done; allow {A(1)x4, STG0}
    LOADA(1); STG(0); LOADB(1, 0, 1); WAITV(5, 4); MM(0, 0, 0);
              LOADB(0, 1, 0);        WAITL(4);     MM(0, 1, 1);
    // t=1..6: force A(t)@prev done; allow {STG(t-1), A(t+1)x4, STG(t)} -> 2-tap STG window
    LOADA(0); STG(1); LOADB(1, 1, 1); WAITV(6, 4); MM(1, 0, 0);
              LOADB(0, 2, 0);        WAITL(4);     MM(1, 1, 1);
    LOADA(1); STG(2); LOADB(1, 2, 1); WAITV(6, 4); MM(0, 0, 0);
              LOADB(0, 3, 0);        WAITL(4);     MM(0, 1, 1);
    LOADA(0); STG(3); LOADB(1, 3, 1); WAITV(6, 4); MM(1, 0, 0);
              LOADB(0, 4, 0);        WAITL(4);     MM(1, 1, 1);
    LOADA(1); STG(4); LOADB(1, 4, 1); WAITV(6, 4); MM(0, 0, 0);
              LOADB(0, 5, 0);        WAITL(4);     MM(0, 1, 1);
    LOADA(0); STG(5); LOADB(1, 5, 1); WAITV(6, 4); MM(1, 0, 0);
              LOADB(0, 6, 0);        WAITL(4);     MM(1, 1, 1);
    LOADA(1); STG(6); LOADB(1, 6, 1); WAITV(6, 4); MM(0, 0, 0);
              LOADB(0, 7, 0);        WAITL(4);     MM(0, 1, 1);
    // t=7: no STG; allow {STG6, A(8)x4}
    LOADA(0);         LOADB(1, 7, 1); WAITV(5, 4); MM(1, 0, 0);
              LOADB(0, 8, 0);        WAITL(4);     MM(1, 1, 1);
    // t=8: prefetch next cc's A(0); vm(4) forces A(8) + all STGs done pre-barrier
    LOADA(1);         LOADB(1, 8, 1); WAITV(4, 4); MM(0, 0, 0);
                                     WAITV(4, 0);  MM(0, 1, 1);
    __builtin_amdgcn_s_barrier();
    { const char* tmp = lbuf; lbuf = (const char*)stb; stb = (char*)tmp; }
    { short8 t0 = afr1[0]; afr0[0] = t0; t0 = afr1[1]; afr0[1] = t0;
      t0 = afr1[2]; afr0[2] = t0; t0 = afr1[3]; afr0[3] = t0; }
  }
  // peeled cc = 7 (no staging, no barrier)
  {
    LOADB(0, 0, 0);
    LOADA(1); LOADB(1, 0, 1); WAITV(4, 4); MM(0, 0, 0);
              LOADB(0, 1, 0); WAITL(4);    MM(0, 1, 1);
    LOADA(0); LOADB(1, 1, 1); WAITV(4, 4); MM(1, 0, 0);
              LOADB(0, 2, 0); WAITL(4);    MM(1, 1, 1);
    LOADA(1); LOADB(1, 2, 1); WAITV(4, 4); MM(0, 0, 0);
              LOADB(0, 3, 0); WAITL(4);    MM(0, 1, 1);
    LOADA(0); LOADB(1, 3, 1); WAITV(4, 4); MM(1, 0, 0);
              LOADB(0, 4, 0); WAITL(4);    MM(1, 1, 1);
    LOADA(1); LOADB(1, 4, 1); WAITV(4, 4); MM(0, 0, 0);
              LOADB(0, 5, 0); WAITL(4);    MM(0, 1, 1);
    LOADA(0); LOADB(1, 5, 1); WAITV(4, 4); MM(1, 0, 0);
              LOADB(0, 6, 0); WAITL(4);    MM(1, 1, 1);
    LOADA(1); LOADB(1, 6, 1); WAITV(4, 4); MM(0, 0, 0);
              LOADB(0, 7, 0); WAITL(4);    MM(0, 1, 1);
    LOADA(0); LOADB(1, 7, 1); WAITV(4, 4); MM(1, 0, 0);
              LOADB(0, 8, 0); WAITL(4);    MM(1, 1, 1);
              LOADB(1, 8, 1); WAITV(0, 4); MM(0, 0, 0);
                              WAITL(0);    MM(0, 1, 1);
  }

  // epilogue: bias + instance-norm + blend; C/D: col=lane&15, row=(lane>>4)*4+reg
  #pragma unroll
  for (int mf = 0; mf < 4; ++mf) {
    int vbase = mt * 256 + wid * 64 + mf * 16 + hi * 4;
    #pragma unroll
    for (int p = 0; p < 2; ++p) {
      int c = (vbase >> 1) + p;
      float bg = bias[c], bb = bias[256 + c];
      float mean = stats[b * 256 + c], rs = stats[1024 + b * 256 + c];
      const float* xrow = x + ((size_t)(b * 256 + c) * 128 + h0) * 256 + w0;
      float* orow = out + ((size_t)(b * 256 + c) * 128 + h0) * 256 + w0;
      #pragma unroll
      for (int nf = 0; nf < 8; ++nf) {
        int pix = nf * 16 + lo;
        float g  = acc[mf][nf][2 * p]     + bg;
        float bt = acc[mf][nf][2 * p + 1] + bb;
        float xv = xrow[pix];
        orow[pix] = (xv - mean) * rs * (1.f + g) + bt;
      }
    }
  }
}

extern "C" void kernel_launch(void* const* d_in, const int* in_sizes, int n_in,
                              void* d_out, int out_size, void* d_ws, size_t ws_size,
                              hipStream_t stream)
{
  const float* x    = (const float*)d_in[0];
  const int*   seg  = (const int*)d_in[1];
  const float* sty  = (const float*)d_in[2];
  const float* fcw  = (const float*)d_in[3];
  const float* fcb  = (const float*)d_in[4];
  const float* cgw  = (const float*)d_in[5];
  const float* cgb  = (const float*)d_in[6];
  const float* cbw  = (const float*)d_in[7];
  const float* cbb  = (const float*)d_in[8];
  const float* mlpw = (const float*)d_in[9];
  const float* mlpb = (const float*)d_in[10];
  const float* sgw  = (const float*)d_in[11];
  const float* sgb  = (const float*)d_in[12];
  const float* sbw  = (const float*)d_in[13];
  const float* sbb  = (const float*)d_in[14];
  const float* blg  = (const float*)d_in[15];
  const float* blb  = (const float*)d_in[16];
  float* out = (float*)d_out;

  char* ws = (char*)d_ws;
  const size_t U_BYTES = (size_t)4 * HP * WPAD * CIN * 2;   // 68,689,920
  size_t off = 0;
  unsigned short* U = (unsigned short*)(ws + off); off += U_BYTES + 262144;  // pad: row-24 overshoot reads
  char* Wp   = ws + off;           off += (size_t)512 * 256 * 9 * 2;  // 2,359,296
  float* mu  = (float*)(ws + off); off += (size_t)4 * 35 * 128 * 4;   // 71,680
  float* mlpT= (float*)(ws + off); off += (size_t)35 * 9 * 128 * 4;   // 161,280
  float* bias= (float*)(ws + off); off += 2048;
  float* stats=(float*)(ws + off); off += 8192;
  if (ws_size < off) return;

  k_pre <<<dim3(298),   dim3(256), 0, stream>>>(
      sty, fcw, fcb, mu, mlpw, mlpT, cgb, cbb, sgb, sbb, blg, blb, bias);
  k_mid <<<dim3(18371), dim3(256), 0, stream>>>(
      x, stats, seg, mu, mlpT, mlpb, U, cgw, cbw, sgw, sbw, blg, blb,
      (unsigned short*)Wp);
  k_conv<<<dim3(2048),  dim3(256), 0, stream>>>(
      x, (const uint4*)U, Wp, bias, stats, out);
}